// Round 19
// baseline (226.657 us; speedup 1.0000x reference)
//
#include <hip/hip_runtime.h>
#include <hip/hip_bf16.h>
#include <cstdint>
#include <cstddef>

// Problem constants
constexpr int HIDDEN = 2048;
constexpr int HEADS  = 16;
constexpr int HD     = 128;       // head dim
constexpr int BATCH  = 2;
constexpr int SEQ    = 2048;
constexpr int MROWS  = BATCH * SEQ;   // 4096 rows for all GEMMs

typedef __attribute__((ext_vector_type(8))) short bf16x8;
typedef __attribute__((ext_vector_type(4))) float f32x4;
typedef __attribute__((ext_vector_type(4))) unsigned u32x4;

constexpr float QSCALE = 0.08838834764831845f * 1.4426950408889634f;  // 1/sqrt(128)*log2e

__device__ __forceinline__ unsigned short f2bf(float f) {
  union { float f; unsigned int u; } c; c.f = f;
  unsigned int r = c.u + 0x7FFFu + ((c.u >> 16) & 1u);
  return (unsigned short)(r >> 16);
}
__device__ __forceinline__ float bf2f(unsigned short u) {
  union { unsigned int u; float f; } c; c.u = ((unsigned int)u) << 16;
  return c.f;
}

__device__ __forceinline__ void gload_lds16(const void* g, void* l) {
  __builtin_amdgcn_global_load_lds(
      (const __attribute__((address_space(1))) void*)g,
      (__attribute__((address_space(3))) void*)l, 16, 0, 0);
}

// ---------------- fp32 -> bf16 conversion: x + all 4 weights, one launch ----
__global__ void k_cvt_all(const float* __restrict__ x,
                          const float* __restrict__ w0, const float* __restrict__ w1,
                          const float* __restrict__ w2, const float* __restrict__ w3,
                          unsigned short* __restrict__ out) {
  constexpr int N4X = MROWS * HIDDEN / 4;    // 2,097,152
  constexpr int N4W = HIDDEN * HIDDEN / 4;   // 1,048,576 = 2^20
  int idx = blockIdx.x * 256 + threadIdx.x;  // N4X + 4*N4W threads
  const float* src;
  int off;
  if (idx < N4X) { src = x; off = idx; }
  else {
    int j = idx - N4X;
    int seg = j >> 20;
    off = j & (N4W - 1);
    src = (seg == 0) ? w0 : (seg == 1) ? w1 : (seg == 2) ? w2 : w3;
  }
  float4 v = reinterpret_cast<const float4*>(src)[off];
  ushort4 o;
  o.x = f2bf(v.x); o.y = f2bf(v.y); o.z = f2bf(v.z); o.w = f2bf(v.w);
  reinterpret_cast<ushort4*>(out)[idx] = o;
}

constexpr int GK  = 2048;
constexpr int GNT = GK / 64;      // 32 K-tiles

// ---------------- pipelined NT GEMM (all 3 GEMMs) --------------------------
// MODE 0: fused QK projection + FUSED ROPE -> bf16 [B,H,S,D] (strip remap).
// MODE 2: fp32 row-major [M, 2048] (final output)
// MODE 3: V^T projection (A=Wv, B=x) -> bf16 [B,H,D,S]
template<int MODE, int BM, int BN>
__global__ __launch_bounds__(512)
__attribute__((amdgpu_waves_per_eu(2)))
void k_gemm256(const unsigned short* __restrict__ A,
               const unsigned short* __restrict__ Bm,
               void* __restrict__ Cout) {
  constexpr int ABYTES = BM * 64 * 2;
  constexpr int BBYTES = BN * 64 * 2;
  constexpr int AG = BM / 64;
  constexpr int BG = BN / 64;
  constexpr int G  = AG + BG;
  constexpr int MI = BM / 32;
  constexpr int NI = BN / 64;

  __shared__ char lds[2 * (ABYTES + BBYTES)];
  char* ldsA = lds;
  char* ldsB = lds + 2 * ABYTES;

  const int t    = threadIdx.x;
  const int lane = t & 63;
  const int w    = t >> 6;
  const int wr   = w >> 2;
  const int wc   = w & 3;
  const int l15  = lane & 15, lg = lane >> 4;

  const int orig = blockIdx.x;
  const int wg   = (orig & 7) * 32 + (orig >> 3);
  const int m0   = (wg >> 4) * BM;
  const int n0   = (wg & 15) * BN;

  const int rowA = t >> 3;
  const int xsel = ((t & 7) ^ (rowA & 7)) * 8;
  const unsigned short* aS = A  + (size_t)(m0 + rowA) * GK + xsel;
  const unsigned short* bS = Bm + (size_t)(n0 + rowA) * GK + xsel;
  char* aD = ldsA + t * 16;
  char* bD = ldsB + t * 16;

#define STAGEG(buf, kt) do {                                       \
    const unsigned short* ap = aS + (kt) * 64;                     \
    const unsigned short* bp = bS + (kt) * 64;                     \
    char* ad = aD + (buf) * ABYTES;                                \
    char* bd = bD + (buf) * BBYTES;                                \
    _Pragma("unroll")                                              \
    for (int g = 0; g < AG; ++g)                                   \
      gload_lds16(ap + (size_t)g * 64 * GK, ad + g * 8192);        \
    _Pragma("unroll")                                              \
    for (int g = 0; g < BG; ++g)                                   \
      gload_lds16(bp + (size_t)g * 64 * GK, bd + g * 8192);        \
  } while (0)

  const int xr  = (l15 & 7) << 4;
  const int vo0 = (lg * 16) ^ xr;
  const int vo1 = (64 + lg * 16) ^ xr;
  const char* aR = ldsA + wr * (BM / 2) * 128 + l15 * 128;
  // MODE 0: strip-interleaved B rows (strip = wc + (ni&1)*4 + (ni>>1)*8)
  const char* bR = (MODE == 0) ? (ldsB + wc * 2048 + l15 * 128)
                               : (ldsB + wc * (BN / 4) * 128 + l15 * 128);
#define BOFF(ni) ((MODE == 0) ? (((ni) & 1) * 8192 + ((ni) >> 1) * 16384) : ((ni) * 2048))

  f32x4 acc[MI][NI];
#pragma unroll
  for (int mi = 0; mi < MI; ++mi)
#pragma unroll
    for (int ni = 0; ni < NI; ++ni)
#pragma unroll
      for (int r = 0; r < 4; ++r) acc[mi][ni][r] = 0.f;

  STAGEG(0, 0);
  STAGEG(1, 1);
  asm volatile("s_waitcnt vmcnt(%0)" :: "i"(G) : "memory");
  __builtin_amdgcn_s_barrier();
  asm volatile("" ::: "memory");

#pragma unroll 1
  for (int kt = 0; kt < GNT; ++kt) {
    const int buf = kt & 1;
    const char* a = aR + buf * ABYTES;
    const char* b = bR + buf * BBYTES;

    bf16x8 af0[MI], bf0[NI];
#pragma unroll
    for (int mi = 0; mi < MI; ++mi)
      af0[mi] = *reinterpret_cast<const bf16x8*>(a + mi * 2048 + vo0);
#pragma unroll
    for (int ni = 0; ni < NI; ++ni)
      bf0[ni] = *reinterpret_cast<const bf16x8*>(b + BOFF(ni) + vo0);
    __builtin_amdgcn_s_setprio(1);
#pragma unroll
    for (int mi = 0; mi < MI; ++mi)
#pragma unroll
      for (int ni = 0; ni < NI; ++ni)
        acc[mi][ni] = __builtin_amdgcn_mfma_f32_16x16x32_bf16(af0[mi], bf0[ni], acc[mi][ni], 0, 0, 0);
    __builtin_amdgcn_s_setprio(0);

    bf16x8 af1[MI], bf1[NI];
#pragma unroll
    for (int mi = 0; mi < MI; ++mi)
      af1[mi] = *reinterpret_cast<const bf16x8*>(a + mi * 2048 + vo1);
#pragma unroll
    for (int ni = 0; ni < NI; ++ni)
      bf1[ni] = *reinterpret_cast<const bf16x8*>(b + BOFF(ni) + vo1);

    asm volatile("s_waitcnt lgkmcnt(0)" ::: "memory");
    __builtin_amdgcn_s_barrier();
    asm volatile("" ::: "memory");

    if (kt < GNT - 2) STAGEG(buf, kt + 2);

    __builtin_amdgcn_s_setprio(1);
#pragma unroll
    for (int mi = 0; mi < MI; ++mi)
#pragma unroll
      for (int ni = 0; ni < NI; ++ni)
        acc[mi][ni] = __builtin_amdgcn_mfma_f32_16x16x32_bf16(af1[mi], bf1[ni], acc[mi][ni], 0, 0, 0);
    __builtin_amdgcn_s_setprio(0);

    if (kt < GNT - 2) asm volatile("s_waitcnt vmcnt(%0)" :: "i"(G) : "memory");
    else              asm volatile("s_waitcnt vmcnt(0)" ::: "memory");
    __builtin_amdgcn_s_barrier();
    asm volatile("" ::: "memory");
  }
#undef STAGEG
#undef BOFF

  if (MODE == 0) {
    // ---- fully in-register fused RoPE epilogue ----
    const int dp = wc * 16 + l15;
    const float invf = exp2f((float)dp * -0.20762050593046868f);
    const int colbase = n0 + wc * 16 + l15;
#pragma unroll
    for (int mi = 0; mi < MI; ++mi) {
#pragma unroll
      for (int r = 0; r < 4; ++r) {
        int row = m0 + wr * 128 + mi * 16 + lg * 4 + r;
        int s  = row & (SEQ - 1);
        int bb = row >> 11;
        float sn, cs;
        __sincosf((float)s * invf, &sn, &cs);
#pragma unroll
        for (int p = 0; p < 2; ++p) {
          float lo = acc[mi][p * 2][r], hi = acc[mi][p * 2 + 1][r];
          float olo = lo * cs - hi * sn;
          float ohi = hi * cs + lo * sn;
          int col   = colbase + p * 128;
          int which = col >> 11;
          int h     = (col & 2047) >> 7;
          if (which == 0) { olo *= QSCALE; ohi *= QSCALE; }
          size_t base = (size_t)which * ((size_t)MROWS * HIDDEN)
                      + ((size_t)(bb * HEADS + h) * SEQ + s) * HD + dp;
          reinterpret_cast<unsigned short*>(Cout)[base]      = f2bf(olo);
          reinterpret_cast<unsigned short*>(Cout)[base + 64] = f2bf(ohi);
        }
      }
    }
  } else {
#pragma unroll
    for (int mi = 0; mi < MI; ++mi) {
#pragma unroll
      for (int ni = 0; ni < NI; ++ni) {
#pragma unroll
        for (int r = 0; r < 4; ++r) {
          int row = m0 + wr * (BM / 2) + mi * 16 + lg * 4 + r;
          int col = n0 + wc * (BN / 4) + ni * 16 + l15;
          float v = acc[mi][ni][r];
          if (MODE == 2) {
            reinterpret_cast<float*>(Cout)[(size_t)row * 2048 + col] = v;
          } else {  // MODE 3: row = output dim o; col = b*SEQ + s
            int h = row >> 7, d = row & (HD - 1);
            int bb = col >> 11, s = col & (SEQ - 1);
            size_t addr = ((size_t)(bb * HEADS + h) * HD + d) * SEQ + s;
            reinterpret_cast<unsigned short*>(Cout)[addr] = f2bf(v);
          }
        }
      }
    }
  }
}

// ---------------- causal flash attention (v11: cross-tile pipeline) --------
// v11 vs v8: in-wave software pipeline -- QK(t+1) MFMA computed while tile
// t's softmax (VALU) + PV run; the two are independent -> MFMA/VALU co-issue.
// K staged 2 tiles ahead (K(t+2) overwrites K(t), dead since iter t-1,
// behind the bottom barrier); V 1 ahead as before.  Barrier skeleton and
// vmcnt(4) counting identical to the proven v8 schedule.
constexpr int QB  = 128;
constexpr int KVB = 64;
constexpr int NQT = SEQ / QB;

__global__ __launch_bounds__(512)
__attribute__((amdgpu_waves_per_eu(4, 4)))
void k_attn(const unsigned short* __restrict__ Q,
            const unsigned short* __restrict__ Kk,
            const unsigned short* __restrict__ Vt,
            unsigned short* __restrict__ O) {
  __shared__ char lds[2 * 16384 + 2 * 16384];   // K dbuf + V dbuf = 64 KB
  char* Ks = lds;
  char* Vs = lds + 2 * 16384;

  const int t    = threadIdx.x;
  const int lane = t & 63;
  const int w    = t >> 6;
  const int l15  = lane & 15, lg = lane >> 4;

  // XCD grouping (bijective): logical = (lin&7)*64 + (lin>>3)
  const int lin     = blockIdx.x + 16 * blockIdx.y;   // 0..511
  const int pos     = lin >> 3;                       // 0..63 within XCD
  const int logical = (lin & 7) * 64 + pos;
  const int bh      = logical >> 4;                   // 4 consecutive bh per XCD
  const int qt0     = logical & 15;
  const int qt      = (pos < 32) ? qt0 : (15 - qt0);  // CU-pair balance
  const int b  = bh >> 4, h = bh & 15;
  const int q0b  = qt * QB;
  const int q0w  = q0b + w * 16;
  const int qw_hi = q0w + 15;

  const unsigned short* Qb = Q  + (size_t)bh * SEQ * HD;
  const unsigned short* Kb = Kk + (size_t)bh * SEQ * HD;
  const unsigned short* Vb = Vt + (size_t)bh * HD * SEQ;

  bf16x8 qf[4];
#pragma unroll
  for (int c = 0; c < 4; ++c)
    qf[c] = *reinterpret_cast<const bf16x8*>(Qb + (size_t)(q0w + l15) * HD + c * 32 + lg * 8);

  float m = -1e30f, lpart = 0.f;
  f32x4 oacc[8];
#pragma unroll
  for (int dt = 0; dt < 8; ++dt)
#pragma unroll
    for (int r = 0; r < 4; ++r) oacc[dt][r] = 0.f;

  const int sp     = t * 16;
  const int srow   = sp >> 8;
  const int scolb  = (sp & 255) ^ ((srow & 7) << 4);
  const unsigned short* ksrc2 = Kb + (size_t)srow * HD + (scolb >> 1);
  char* kdst2 = Ks + sp;

  const int vrow  = t >> 3;
  const int vcolb = ((t & 7) << 4) ^ ((vrow & 7) << 4);
  const unsigned short* vsrc = Vb + (size_t)vrow * SEQ + (vcolb >> 1);
  char* vdst = Vs + t * 16;

  const int nb = q0b / KVB + 2;   // nb >= 2

#define ISSUE_K(tile) do {                                              \
    char* nk = kdst2 + ((tile) & 1) * 16384;                            \
    gload_lds16(ksrc2 + (size_t)((tile) * KVB) * HD, nk);               \
    gload_lds16(ksrc2 + (size_t)((tile) * KVB + 32) * HD, nk + 8192);   \
  } while (0)
#define ISSUE_V(tile) do {                                              \
    char* nv = vdst + ((tile) & 1) * 16384;                             \
    gload_lds16(vsrc + (tile) * KVB, nv);                               \
    gload_lds16(vsrc + (size_t)64 * SEQ + (tile) * KVB, nv + 8192);     \
  } while (0)

  // QK^T of one tile from LDS buffer kbuf into sc (SWAPPED: A=K, B=Q)
#define QKT(sc, kbuf) do {                                              \
    const char* Kc = Ks + (kbuf) * 16384;                               \
    _Pragma("unroll")                                                   \
    for (int tt = 0; tt < 4; ++tt) {                                    \
      const int kr = tt * 16 + l15;                                     \
      const int xr = (kr & 7) << 4;                                     \
      _Pragma("unroll")                                                 \
      for (int c = 0; c < 4; ++c) {                                     \
        bf16x8 kf = *reinterpret_cast<const bf16x8*>(                   \
            Kc + kr * 256 + ((c * 64 + lg * 16) ^ xr));                 \
        sc[tt] = __builtin_amdgcn_mfma_f32_16x16x32_bf16(kf, qf[c], sc[tt], 0, 0, 0); \
      }                                                                 \
    }                                                                   \
  } while (0)

  // prologue: K(0), V(0), K(1); wait K(0); compute QK(0) into scc
  ISSUE_K(0);
  ISSUE_V(0);
  ISSUE_K(1);
  asm volatile("s_waitcnt vmcnt(4)" ::: "memory");   // K(0) landed
  __builtin_amdgcn_s_barrier();
  asm volatile("" ::: "memory");

  f32x4 scc[4];
#pragma unroll
  for (int tt = 0; tt < 4; ++tt)
#pragma unroll
    for (int r = 0; r < 4; ++r) scc[tt][r] = 0.f;
  __builtin_amdgcn_s_setprio(1);
  QKT(scc, 0);
  __builtin_amdgcn_s_setprio(0);

  for (int kb = 0; kb < nb; ++kb) {
    const int kv0 = kb * KVB;
    // stage ahead: V(kb+1), K(kb+2); counted vmcnt leaves them in flight
    if (kb + 2 < nb) {
      ISSUE_V(kb + 1);
      ISSUE_K(kb + 2);
      asm volatile("s_waitcnt vmcnt(4)" ::: "memory");   // K(kb+1), V(kb) landed
    } else if (kb + 1 < nb) {
      ISSUE_V(kb + 1);
      asm volatile("s_waitcnt vmcnt(2)" ::: "memory");
    } else {
      asm volatile("s_waitcnt vmcnt(0)" ::: "memory");
    }
    __builtin_amdgcn_s_barrier();      // all waves: K(kb+1) + V(kb) visible
    asm volatile("" ::: "memory");

    // ---- QK(kb+1) into scn (overlaps tile-kb softmax below) ----
    f32x4 scn[4];
    const bool doNext = (kb + 1 < nb) && (kv0 + KVB <= qw_hi);
    if (doNext) {
#pragma unroll
      for (int tt = 0; tt < 4; ++tt)
#pragma unroll
        for (int r = 0; r < 4; ++r) scn[tt][r] = 0.f;
      QKT(scn, (kb + 1) & 1);
    }

    // ---- softmax + PV for tile kb ----
    if (kv0 <= qw_hi) {
      const bool full = (kv0 + KVB - 1 <= q0w);
      const int qg = q0w + l15;
      if (!full) {
        const int kvb = kv0 + lg * 4;
#pragma unroll
        for (int tt = 0; tt < 4; ++tt)
#pragma unroll
          for (int r = 0; r < 4; ++r)
            if (kvb + tt * 16 + r > qg) scc[tt][r] = -1e30f;
      }
      float pm01 = fmaxf(fmaxf(scc[0][0], scc[0][1]), fmaxf(scc[0][2], scc[0][3]));
      float pm11 = fmaxf(fmaxf(scc[1][0], scc[1][1]), fmaxf(scc[1][2], scc[1][3]));
      float pm21 = fmaxf(fmaxf(scc[2][0], scc[2][1]), fmaxf(scc[2][2], scc[2][3]));
      float pm31 = fmaxf(fmaxf(scc[3][0], scc[3][1]), fmaxf(scc[3][2], scc[3][3]));
      float pm = fmaxf(fmaxf(pm01, pm11), fmaxf(pm21, pm31));
      if (__any(pm > m + 11.5f)) {               // rare
        float pmr = pm;
        pmr = fmaxf(pmr, __shfl_xor(pmr, 16));
        pmr = fmaxf(pmr, __shfl_xor(pmr, 32));
        float mn = fmaxf(m, pmr);
        float al = exp2f(m - mn);
        lpart *= al;
#pragma unroll
        for (int r = 0; r < 4; ++r) {
          float alr = __shfl(al, lg * 4 + r, 16);
#pragma unroll
          for (int dt = 0; dt < 8; ++dt) oacc[dt][r] *= alr;
        }
        m = mn;
      }
      float ps = 0.f;
#pragma unroll
      for (int tt = 0; tt < 4; ++tt)
#pragma unroll
        for (int r = 0; r < 4; ++r) {
          scc[tt][r] = exp2f(scc[tt][r] - m);   // P in place of S
          ps += scc[tt][r];
        }
      lpart += ps;

      // ---- P -> bf16 pairs + permlane redistribution ----
      unsigned cc[4][2];
#pragma unroll
      for (int tt = 0; tt < 4; ++tt) {
        asm("v_cvt_pk_bf16_f32 %0, %1, %2" : "=v"(cc[tt][0]) : "v"(scc[tt][0]), "v"(scc[tt][1]));
        asm("v_cvt_pk_bf16_f32 %0, %1, %2" : "=v"(cc[tt][1]) : "v"(scc[tt][2]), "v"(scc[tt][3]));
      }
      u32x4 u0, u1;
      {
        unsigned a0 = cc[0][0], b0 = cc[1][0];
        asm("v_permlane32_swap_b32 %0, %1" : "+v"(a0), "+v"(b0));
        asm("v_permlane16_swap_b32 %0, %1" : "+v"(a0), "+v"(b0));
        unsigned a1 = cc[0][1], b1 = cc[1][1];
        asm("v_permlane32_swap_b32 %0, %1" : "+v"(a1), "+v"(b1));
        asm("v_permlane16_swap_b32 %0, %1" : "+v"(a1), "+v"(b1));
        u0[0] = a0; u0[1] = a1; u0[2] = b0; u0[3] = b1;
        unsigned a2 = cc[2][0], b2 = cc[3][0];
        asm("v_permlane32_swap_b32 %0, %1" : "+v"(a2), "+v"(b2));
        asm("v_permlane16_swap_b32 %0, %1" : "+v"(a2), "+v"(b2));
        unsigned a3 = cc[2][1], b3 = cc[3][1];
        asm("v_permlane32_swap_b32 %0, %1" : "+v"(a3), "+v"(b3));
        asm("v_permlane16_swap_b32 %0, %1" : "+v"(a3), "+v"(b3));
        u1[0] = a2; u1[1] = a3; u1[2] = b2; u1[3] = b3;
      }
      bf16x8 pa0 = __builtin_bit_cast(bf16x8, u0);
      bf16x8 pa1 = __builtin_bit_cast(bf16x8, u1);

      // ---- PV (V from swizzled LDS, buffer kb&1) ----
      const char* Vc = Vs + (kb & 1) * 16384;
      const int xv = (l15 & 7) << 4;
      __builtin_amdgcn_s_setprio(1);
#pragma unroll
      for (int dt = 0; dt < 8; ++dt) {
        const char* vrl = Vc + (dt * 16 + l15) * 128;
        bf16x8 vf0 = *reinterpret_cast<const bf16x8*>(vrl + ((lg * 16) ^ xv));
        bf16x8 vf1 = *reinterpret_cast<const bf16x8*>(vrl + ((64 + lg * 16) ^ xv));
        oacc[dt] = __builtin_amdgcn_mfma_f32_16x16x32_bf16(pa0, vf0, oacc[dt], 0, 0, 0);
        oacc[dt] = __builtin_amdgcn_mfma_f32_16x16x32_bf16(pa1, vf1, oacc[dt], 0, 0, 0);
      }
      __builtin_amdgcn_s_setprio(0);
    }
    __builtin_amdgcn_s_barrier();        // all waves done reading buffers
    asm volatile("" ::: "memory");

    // roll pipeline: scn -> scc (dead when doNext false)
#pragma unroll
    for (int tt = 0; tt < 4; ++tt)
#pragma unroll
      for (int r = 0; r < 4; ++r) scc[tt][r] = scn[tt][r];
  }
#undef QKT
#undef ISSUE_K
#undef ISSUE_V

  float ls = lpart;
  ls += __shfl_xor(ls, 16);
  ls += __shfl_xor(ls, 32);
  float inv = 1.0f / ls;
  float invr[4];
#pragma unroll
  for (int r = 0; r < 4; ++r) invr[r] = __shfl(inv, lg * 4 + r, 16);
#pragma unroll
  for (int dt = 0; dt < 8; ++dt) {
#pragma unroll
    for (int r = 0; r < 4; ++r) {
      int qg = q0w + lg * 4 + r;
      int dv = dt * 16 + l15;
      O[((size_t)(b * SEQ + qg) * HEADS + h) * HD + dv] = f2bf(oacc[dt][r] * invr[r]);
    }
  }
}

// ---------------- launch ----------------
extern "C" void kernel_launch(void* const* d_in, const int* in_sizes, int n_in,
                              void* d_out, int out_size, void* d_ws, size_t ws_size,
                              hipStream_t stream) {
  (void)in_sizes; (void)n_in; (void)out_size; (void)ws_size;
  const float* x  = (const float*)d_in[0];
  const float* Wq = (const float*)d_in[1];
  const float* Wk = (const float*)d_in[2];
  const float* Wv = (const float*)d_in[3];
  const float* Wo = (const float*)d_in[4];
  float* out = (float*)d_out;

  unsigned short* xb  = (unsigned short*)d_ws;
  unsigned short* wqb = xb  + (size_t)MROWS * HIDDEN;
  unsigned short* wkb = wqb + (size_t)HIDDEN * HIDDEN;
  unsigned short* wvb = wkb + (size_t)HIDDEN * HIDDEN;
  unsigned short* wob = wvb + (size_t)HIDDEN * HIDDEN;
  unsigned short* Qb  = wob + (size_t)HIDDEN * HIDDEN;
  unsigned short* Kb  = Qb  + (size_t)MROWS * HIDDEN;
  unsigned short* Vtb = Kb  + (size_t)MROWS * HIDDEN;
  unsigned short* Ob  = Vtb + (size_t)MROWS * HIDDEN;
  (void)wkb;

  constexpr int CVT_THREADS = (MROWS * HIDDEN + 4 * HIDDEN * HIDDEN) / 4;
  k_cvt_all<<<CVT_THREADS / 256, 256, 0, stream>>>(x, Wq, Wk, Wv, Wo, xb);

  // fused Q+K projection + RoPE: 256x256 pipelined, 256 blocks
  k_gemm256<0, 256, 256><<<256, 512, 0, stream>>>(xb, wqb, Qb);
  // V^T projection: 128x256 pipelined (A=Wv, B=x), 256 blocks
  k_gemm256<3, 128, 256><<<256, 512, 0, stream>>>(wvb, xb, Vtb);

  k_attn<<<dim3(SEQ / QB, BATCH * HEADS), 512, 0, stream>>>(Qb, Kb, Vtb, Ob);

  // output projection: 256x128 pipelined, 256 blocks
  k_gemm256<2, 256, 128><<<256, 512, 0, stream>>>(Ob, wob, out);
}

// Round 20
// 225.585 us; speedup vs baseline: 1.0048x; 1.0048x over previous
//
#include <hip/hip_runtime.h>
#include <hip/hip_bf16.h>
#include <cstdint>
#include <cstddef>

// Problem constants
constexpr int HIDDEN = 2048;
constexpr int HEADS  = 16;
constexpr int HD     = 128;       // head dim
constexpr int BATCH  = 2;
constexpr int SEQ    = 2048;
constexpr int MROWS  = BATCH * SEQ;   // 4096 rows for all GEMMs

typedef __attribute__((ext_vector_type(8))) short bf16x8;
typedef __attribute__((ext_vector_type(4))) float f32x4;
typedef __attribute__((ext_vector_type(4))) unsigned u32x4;

constexpr float QSCALE = 0.08838834764831845f * 1.4426950408889634f;  // 1/sqrt(128)*log2e

__device__ __forceinline__ unsigned short f2bf(float f) {
  union { float f; unsigned int u; } c; c.f = f;
  unsigned int r = c.u + 0x7FFFu + ((c.u >> 16) & 1u);
  return (unsigned short)(r >> 16);
}
__device__ __forceinline__ float bf2f(unsigned short u) {
  union { unsigned int u; float f; } c; c.u = ((unsigned int)u) << 16;
  return c.f;
}

__device__ __forceinline__ void gload_lds16(const void* g, void* l) {
  __builtin_amdgcn_global_load_lds(
      (const __attribute__((address_space(1))) void*)g,
      (__attribute__((address_space(3))) void*)l, 16, 0, 0);
}

// ---------------- fp32 -> bf16 conversion: x + all 4 weights, one launch ----
__global__ void k_cvt_all(const float* __restrict__ x,
                          const float* __restrict__ w0, const float* __restrict__ w1,
                          const float* __restrict__ w2, const float* __restrict__ w3,
                          unsigned short* __restrict__ out) {
  constexpr int N4X = MROWS * HIDDEN / 4;    // 2,097,152
  constexpr int N4W = HIDDEN * HIDDEN / 4;   // 1,048,576 = 2^20
  int idx = blockIdx.x * 256 + threadIdx.x;  // N4X + 4*N4W threads
  const float* src;
  int off;
  if (idx < N4X) { src = x; off = idx; }
  else {
    int j = idx - N4X;
    int seg = j >> 20;
    off = j & (N4W - 1);
    src = (seg == 0) ? w0 : (seg == 1) ? w1 : (seg == 2) ? w2 : w3;
  }
  float4 v = reinterpret_cast<const float4*>(src)[off];
  ushort4 o;
  o.x = f2bf(v.x); o.y = f2bf(v.y); o.z = f2bf(v.z); o.w = f2bf(v.w);
  reinterpret_cast<ushort4*>(out)[idx] = o;
}

constexpr int GK  = 2048;
constexpr int GNT = GK / 64;      // 32 K-tiles

// ---------------- pipelined NT GEMM (all 3 GEMMs) --------------------------
// MODE 0: fused QK projection + FUSED ROPE -> bf16 [B,H,S,D].
//         Wave-strip remap: wave wc owns 16-col strips {wc, wc+4, wc+8, wc+12}
//         of the 256-col tile, so RoPE pairs (d, d+64) are ni=0/1 and ni=2/3
//         IN THE SAME LANE -> in-register rotation, no LDS exchange, and one
//         inv_freq + 32 sincos per thread (s depends only on (mi,r)).
// MODE 2: fp32 row-major [M, 2048] (final output)
// MODE 3: V^T projection (A=Wv, B=x) -> bf16 [B,H,D,S]
template<int MODE, int BM, int BN>
__global__ __launch_bounds__(512)
__attribute__((amdgpu_waves_per_eu(2)))
void k_gemm256(const unsigned short* __restrict__ A,
               const unsigned short* __restrict__ Bm,
               void* __restrict__ Cout) {
  constexpr int ABYTES = BM * 64 * 2;
  constexpr int BBYTES = BN * 64 * 2;
  constexpr int AG = BM / 64;
  constexpr int BG = BN / 64;
  constexpr int G  = AG + BG;
  constexpr int MI = BM / 32;
  constexpr int NI = BN / 64;

  __shared__ char lds[2 * (ABYTES + BBYTES)];
  char* ldsA = lds;
  char* ldsB = lds + 2 * ABYTES;

  const int t    = threadIdx.x;
  const int lane = t & 63;
  const int w    = t >> 6;
  const int wr   = w >> 2;
  const int wc   = w & 3;
  const int l15  = lane & 15, lg = lane >> 4;

  const int orig = blockIdx.x;
  const int wg   = (orig & 7) * 32 + (orig >> 3);
  const int m0   = (wg >> 4) * BM;
  const int n0   = (wg & 15) * BN;

  const int rowA = t >> 3;
  const int xsel = ((t & 7) ^ (rowA & 7)) * 8;
  const unsigned short* aS = A  + (size_t)(m0 + rowA) * GK + xsel;
  const unsigned short* bS = Bm + (size_t)(n0 + rowA) * GK + xsel;
  char* aD = ldsA + t * 16;
  char* bD = ldsB + t * 16;

#define STAGEG(buf, kt) do {                                       \
    const unsigned short* ap = aS + (kt) * 64;                     \
    const unsigned short* bp = bS + (kt) * 64;                     \
    char* ad = aD + (buf) * ABYTES;                                \
    char* bd = bD + (buf) * BBYTES;                                \
    _Pragma("unroll")                                              \
    for (int g = 0; g < AG; ++g)                                   \
      gload_lds16(ap + (size_t)g * 64 * GK, ad + g * 8192);        \
    _Pragma("unroll")                                              \
    for (int g = 0; g < BG; ++g)                                   \
      gload_lds16(bp + (size_t)g * 64 * GK, bd + g * 8192);        \
  } while (0)

  const int xr  = (l15 & 7) << 4;
  const int vo0 = (lg * 16) ^ xr;
  const int vo1 = (64 + lg * 16) ^ xr;
  const char* aR = ldsA + wr * (BM / 2) * 128 + l15 * 128;
  // MODE 0: strip-interleaved B rows (strip = wc + (ni&1)*4 + (ni>>1)*8)
  const char* bR = (MODE == 0) ? (ldsB + wc * 2048 + l15 * 128)
                               : (ldsB + wc * (BN / 4) * 128 + l15 * 128);
#define BOFF(ni) ((MODE == 0) ? (((ni) & 1) * 8192 + ((ni) >> 1) * 16384) : ((ni) * 2048))

  f32x4 acc[MI][NI];
#pragma unroll
  for (int mi = 0; mi < MI; ++mi)
#pragma unroll
    for (int ni = 0; ni < NI; ++ni)
#pragma unroll
      for (int r = 0; r < 4; ++r) acc[mi][ni][r] = 0.f;

  STAGEG(0, 0);
  STAGEG(1, 1);
  asm volatile("s_waitcnt vmcnt(%0)" :: "i"(G) : "memory");
  __builtin_amdgcn_s_barrier();
  asm volatile("" ::: "memory");

#pragma unroll 1
  for (int kt = 0; kt < GNT; ++kt) {
    const int buf = kt & 1;
    const char* a = aR + buf * ABYTES;
    const char* b = bR + buf * BBYTES;

    bf16x8 af0[MI], bf0[NI];
#pragma unroll
    for (int mi = 0; mi < MI; ++mi)
      af0[mi] = *reinterpret_cast<const bf16x8*>(a + mi * 2048 + vo0);
#pragma unroll
    for (int ni = 0; ni < NI; ++ni)
      bf0[ni] = *reinterpret_cast<const bf16x8*>(b + BOFF(ni) + vo0);
    __builtin_amdgcn_s_setprio(1);
#pragma unroll
    for (int mi = 0; mi < MI; ++mi)
#pragma unroll
      for (int ni = 0; ni < NI; ++ni)
        acc[mi][ni] = __builtin_amdgcn_mfma_f32_16x16x32_bf16(af0[mi], bf0[ni], acc[mi][ni], 0, 0, 0);
    __builtin_amdgcn_s_setprio(0);

    bf16x8 af1[MI], bf1[NI];
#pragma unroll
    for (int mi = 0; mi < MI; ++mi)
      af1[mi] = *reinterpret_cast<const bf16x8*>(a + mi * 2048 + vo1);
#pragma unroll
    for (int ni = 0; ni < NI; ++ni)
      bf1[ni] = *reinterpret_cast<const bf16x8*>(b + BOFF(ni) + vo1);

    asm volatile("s_waitcnt lgkmcnt(0)" ::: "memory");
    __builtin_amdgcn_s_barrier();
    asm volatile("" ::: "memory");

    if (kt < GNT - 2) STAGEG(buf, kt + 2);

    __builtin_amdgcn_s_setprio(1);
#pragma unroll
    for (int mi = 0; mi < MI; ++mi)
#pragma unroll
      for (int ni = 0; ni < NI; ++ni)
        acc[mi][ni] = __builtin_amdgcn_mfma_f32_16x16x32_bf16(af1[mi], bf1[ni], acc[mi][ni], 0, 0, 0);
    __builtin_amdgcn_s_setprio(0);

    if (kt < GNT - 2) asm volatile("s_waitcnt vmcnt(%0)" :: "i"(G) : "memory");
    else              asm volatile("s_waitcnt vmcnt(0)" ::: "memory");
    __builtin_amdgcn_s_barrier();
    asm volatile("" ::: "memory");
  }
#undef STAGEG
#undef BOFF

  if (MODE == 0) {
    // ---- fully in-register fused RoPE epilogue ----
    const int dp = wc * 16 + l15;
    const float invf = exp2f((float)dp * -0.20762050593046868f);
    const int colbase = n0 + wc * 16 + l15;
#pragma unroll
    for (int mi = 0; mi < MI; ++mi) {
#pragma unroll
      for (int r = 0; r < 4; ++r) {
        int row = m0 + wr * 128 + mi * 16 + lg * 4 + r;
        int s  = row & (SEQ - 1);
        int bb = row >> 11;
        float sn, cs;
        __sincosf((float)s * invf, &sn, &cs);
#pragma unroll
        for (int p = 0; p < 2; ++p) {
          float lo = acc[mi][p * 2][r], hi = acc[mi][p * 2 + 1][r];
          float olo = lo * cs - hi * sn;
          float ohi = hi * cs + lo * sn;
          int col   = colbase + p * 128;
          int which = col >> 11;
          int h     = (col & 2047) >> 7;
          if (which == 0) { olo *= QSCALE; ohi *= QSCALE; }
          size_t base = (size_t)which * ((size_t)MROWS * HIDDEN)
                      + ((size_t)(bb * HEADS + h) * SEQ + s) * HD + dp;
          reinterpret_cast<unsigned short*>(Cout)[base]      = f2bf(olo);
          reinterpret_cast<unsigned short*>(Cout)[base + 64] = f2bf(ohi);
        }
      }
    }
  } else {
#pragma unroll
    for (int mi = 0; mi < MI; ++mi) {
#pragma unroll
      for (int ni = 0; ni < NI; ++ni) {
#pragma unroll
        for (int r = 0; r < 4; ++r) {
          int row = m0 + wr * (BM / 2) + mi * 16 + lg * 4 + r;
          int col = n0 + wc * (BN / 4) + ni * 16 + l15;
          float v = acc[mi][ni][r];
          if (MODE == 2) {
            reinterpret_cast<float*>(Cout)[(size_t)row * 2048 + col] = v;
          } else {  // MODE 3: row = output dim o; col = b*SEQ + s
            int h = row >> 7, d = row & (HD - 1);
            int bb = col >> 11, s = col & (SEQ - 1);
            size_t addr = ((size_t)(bb * HEADS + h) * HD + d) * SEQ + s;
            reinterpret_cast<unsigned short*>(Cout)[addr] = f2bf(v);
          }
        }
      }
    }
  }
}

// ---------------- causal flash attention (v8 = round-18 best) ----------------
// Double-buffered K AND V (64 KB); per tile: {issue K(t+1)+V(t+1); vmcnt(4)
// [tile t landed]; barrier; compute; barrier}.  Swapped QK^T (A=K, B=Q) ->
// per-lane softmax, in-register P via cvt_pk + permlane swaps.  XCD
// bh-grouping keeps K/V L2-resident per XCD; qt mirror balances CU pairs.
constexpr int QB  = 128;
constexpr int KVB = 64;
constexpr int NQT = SEQ / QB;

__global__ __launch_bounds__(512)
__attribute__((amdgpu_waves_per_eu(4, 4)))
void k_attn(const unsigned short* __restrict__ Q,
            const unsigned short* __restrict__ Kk,
            const unsigned short* __restrict__ Vt,
            unsigned short* __restrict__ O) {
  __shared__ char lds[2 * 16384 + 2 * 16384];   // K dbuf + V dbuf = 64 KB
  char* Ks = lds;
  char* Vs = lds + 2 * 16384;

  const int t    = threadIdx.x;
  const int lane = t & 63;
  const int w    = t >> 6;
  const int l15  = lane & 15, lg = lane >> 4;

  // XCD grouping (bijective): logical = (lin&7)*64 + (lin>>3)
  const int lin     = blockIdx.x + 16 * blockIdx.y;   // 0..511
  const int pos     = lin >> 3;                       // 0..63 within XCD
  const int logical = (lin & 7) * 64 + pos;
  const int bh      = logical >> 4;                   // 4 consecutive bh per XCD
  const int qt0     = logical & 15;
  const int qt      = (pos < 32) ? qt0 : (15 - qt0);  // CU-pair balance
  const int b  = bh >> 4, h = bh & 15;
  const int q0b  = qt * QB;
  const int q0w  = q0b + w * 16;
  const int qw_hi = q0w + 15;

  const unsigned short* Qb = Q  + (size_t)bh * SEQ * HD;
  const unsigned short* Kb = Kk + (size_t)bh * SEQ * HD;
  const unsigned short* Vb = Vt + (size_t)bh * HD * SEQ;

  bf16x8 qf[4];
#pragma unroll
  for (int c = 0; c < 4; ++c)
    qf[c] = *reinterpret_cast<const bf16x8*>(Qb + (size_t)(q0w + l15) * HD + c * 32 + lg * 8);

  float m = -1e30f, lpart = 0.f;
  f32x4 oacc[8];
#pragma unroll
  for (int dt = 0; dt < 8; ++dt)
#pragma unroll
    for (int r = 0; r < 4; ++r) oacc[dt][r] = 0.f;

  const int sp     = t * 16;
  const int srow   = sp >> 8;
  const int scolb  = (sp & 255) ^ ((srow & 7) << 4);
  const unsigned short* ksrc2 = Kb + (size_t)srow * HD + (scolb >> 1);
  char* kdst2 = Ks + sp;

  const int vrow  = t >> 3;
  const int vcolb = ((t & 7) << 4) ^ ((vrow & 7) << 4);
  const unsigned short* vsrc = Vb + (size_t)vrow * SEQ + (vcolb >> 1);
  char* vdst = Vs + t * 16;

  const int nb = q0b / KVB + 2;

  // prologue: issue tile 0 (no drain; gated by vmcnt+barrier in iter 0)
  gload_lds16(ksrc2, kdst2);
  gload_lds16(ksrc2 + (size_t)32 * HD, kdst2 + 8192);
  gload_lds16(vsrc, vdst);
  gload_lds16(vsrc + (size_t)64 * SEQ, vdst + 8192);

  int cur = 0;
  for (int kb = 0; kb < nb; ++kb) {
    const int kv0 = kb * KVB;
    // issue next tile, then wait only for THIS tile's 4 loads
    if (kb + 1 < nb) {
      const int nxt = kv0 + KVB;
      char* nk = kdst2 + (cur ^ 1) * 16384;
      char* nv = vdst  + (cur ^ 1) * 16384;
      gload_lds16(ksrc2 + (size_t)nxt * HD, nk);
      gload_lds16(ksrc2 + (size_t)(nxt + 32) * HD, nk + 8192);
      gload_lds16(vsrc + nxt, nv);
      gload_lds16(vsrc + (size_t)64 * SEQ + nxt, nv + 8192);
      asm volatile("s_waitcnt vmcnt(4)" ::: "memory");
    } else {
      asm volatile("s_waitcnt vmcnt(0)" ::: "memory");
    }
    __builtin_amdgcn_s_barrier();        // all waves' tile-kb loads landed
    asm volatile("" ::: "memory");

    if (kv0 <= qw_hi) {
      const char* Kc = Ks + cur * 16384;
      const char* Vc = Vs + cur * 16384;
      // ---- QK^T (SWAPPED: A=K, B=Q) ----
      f32x4 sc[4];
#pragma unroll
      for (int tt = 0; tt < 4; ++tt)
#pragma unroll
        for (int r = 0; r < 4; ++r) sc[tt][r] = 0.f;
      __builtin_amdgcn_s_setprio(1);
#pragma unroll
      for (int tt = 0; tt < 4; ++tt) {
        const int kr = tt * 16 + l15;
        const int xr = (kr & 7) << 4;
#pragma unroll
        for (int c = 0; c < 4; ++c) {
          bf16x8 kf = *reinterpret_cast<const bf16x8*>(
              Kc + kr * 256 + ((c * 64 + lg * 16) ^ xr));
          sc[tt] = __builtin_amdgcn_mfma_f32_16x16x32_bf16(kf, qf[c], sc[tt], 0, 0, 0);
        }
      }
      __builtin_amdgcn_s_setprio(0);
      // lane holds S[kv = kv0 + tt*16 + lg*4 + r][q = q0w + l15]

      // ---- per-lane softmax (log2 domain, defer-max THR 11.5) ----
      const bool full = (kv0 + KVB - 1 <= q0w);
      const int qg = q0w + l15;
      if (!full) {
        const int kvb = kv0 + lg * 4;
#pragma unroll
        for (int tt = 0; tt < 4; ++tt)
#pragma unroll
          for (int r = 0; r < 4; ++r)
            if (kvb + tt * 16 + r > qg) sc[tt][r] = -1e30f;
      }
      float pm01 = fmaxf(fmaxf(sc[0][0], sc[0][1]), fmaxf(sc[0][2], sc[0][3]));
      float pm11 = fmaxf(fmaxf(sc[1][0], sc[1][1]), fmaxf(sc[1][2], sc[1][3]));
      float pm21 = fmaxf(fmaxf(sc[2][0], sc[2][1]), fmaxf(sc[2][2], sc[2][3]));
      float pm31 = fmaxf(fmaxf(sc[3][0], sc[3][1]), fmaxf(sc[3][2], sc[3][3]));
      float pm = fmaxf(fmaxf(pm01, pm11), fmaxf(pm21, pm31));
      if (__any(pm > m + 11.5f)) {               // rare
        float pmr = pm;
        pmr = fmaxf(pmr, __shfl_xor(pmr, 16));
        pmr = fmaxf(pmr, __shfl_xor(pmr, 32));
        float mn = fmaxf(m, pmr);
        float al = exp2f(m - mn);
        lpart *= al;
#pragma unroll
        for (int r = 0; r < 4; ++r) {
          float alr = __shfl(al, lg * 4 + r, 16);
#pragma unroll
          for (int dt = 0; dt < 8; ++dt) oacc[dt][r] *= alr;
        }
        m = mn;
      }
      float p[4][4];
      float ps = 0.f;
#pragma unroll
      for (int tt = 0; tt < 4; ++tt)
#pragma unroll
        for (int r = 0; r < 4; ++r) {
          p[tt][r] = exp2f(sc[tt][r] - m);
          ps += p[tt][r];
        }
      lpart += ps;

      // ---- P -> bf16 pairs + permlane redistribution ----
      unsigned cc[4][2];
#pragma unroll
      for (int tt = 0; tt < 4; ++tt) {
        asm("v_cvt_pk_bf16_f32 %0, %1, %2" : "=v"(cc[tt][0]) : "v"(p[tt][0]), "v"(p[tt][1]));
        asm("v_cvt_pk_bf16_f32 %0, %1, %2" : "=v"(cc[tt][1]) : "v"(p[tt][2]), "v"(p[tt][3]));
      }
      u32x4 u0, u1;
      {
        unsigned a0 = cc[0][0], b0 = cc[1][0];
        asm("v_permlane32_swap_b32 %0, %1" : "+v"(a0), "+v"(b0));
        asm("v_permlane16_swap_b32 %0, %1" : "+v"(a0), "+v"(b0));
        unsigned a1 = cc[0][1], b1 = cc[1][1];
        asm("v_permlane32_swap_b32 %0, %1" : "+v"(a1), "+v"(b1));
        asm("v_permlane16_swap_b32 %0, %1" : "+v"(a1), "+v"(b1));
        u0[0] = a0; u0[1] = a1; u0[2] = b0; u0[3] = b1;
        unsigned a2 = cc[2][0], b2 = cc[3][0];
        asm("v_permlane32_swap_b32 %0, %1" : "+v"(a2), "+v"(b2));
        asm("v_permlane16_swap_b32 %0, %1" : "+v"(a2), "+v"(b2));
        unsigned a3 = cc[2][1], b3 = cc[3][1];
        asm("v_permlane32_swap_b32 %0, %1" : "+v"(a3), "+v"(b3));
        asm("v_permlane16_swap_b32 %0, %1" : "+v"(a3), "+v"(b3));
        u1[0] = a2; u1[1] = a3; u1[2] = b2; u1[3] = b3;
      }
      bf16x8 pa0 = __builtin_bit_cast(bf16x8, u0);
      bf16x8 pa1 = __builtin_bit_cast(bf16x8, u1);

      // ---- PV (V from swizzled LDS) ----
      const int xv = (l15 & 7) << 4;
      __builtin_amdgcn_s_setprio(1);
#pragma unroll
      for (int dt = 0; dt < 8; ++dt) {
        const char* vrl = Vc + (dt * 16 + l15) * 128;
        bf16x8 vf0 = *reinterpret_cast<const bf16x8*>(vrl + ((lg * 16) ^ xv));
        bf16x8 vf1 = *reinterpret_cast<const bf16x8*>(vrl + ((64 + lg * 16) ^ xv));
        oacc[dt] = __builtin_amdgcn_mfma_f32_16x16x32_bf16(pa0, vf0, oacc[dt], 0, 0, 0);
        oacc[dt] = __builtin_amdgcn_mfma_f32_16x16x32_bf16(pa1, vf1, oacc[dt], 0, 0, 0);
      }
      __builtin_amdgcn_s_setprio(0);
    }
    __builtin_amdgcn_s_barrier();        // all waves done reading buf[cur]
    asm volatile("" ::: "memory");
    cur ^= 1;
  }

  float ls = lpart;
  ls += __shfl_xor(ls, 16);
  ls += __shfl_xor(ls, 32);
  float inv = 1.0f / ls;
  float invr[4];
#pragma unroll
  for (int r = 0; r < 4; ++r) invr[r] = __shfl(inv, lg * 4 + r, 16);
#pragma unroll
  for (int dt = 0; dt < 8; ++dt) {
#pragma unroll
    for (int r = 0; r < 4; ++r) {
      int qg = q0w + lg * 4 + r;
      int dv = dt * 16 + l15;
      O[((size_t)(b * SEQ + qg) * HEADS + h) * HD + dv] = f2bf(oacc[dt][r] * invr[r]);
    }
  }
}

// ---------------- launch ----------------
extern "C" void kernel_launch(void* const* d_in, const int* in_sizes, int n_in,
                              void* d_out, int out_size, void* d_ws, size_t ws_size,
                              hipStream_t stream) {
  (void)in_sizes; (void)n_in; (void)out_size; (void)ws_size;
  const float* x  = (const float*)d_in[0];
  const float* Wq = (const float*)d_in[1];
  const float* Wk = (const float*)d_in[2];
  const float* Wv = (const float*)d_in[3];
  const float* Wo = (const float*)d_in[4];
  float* out = (float*)d_out;

  unsigned short* xb  = (unsigned short*)d_ws;
  unsigned short* wqb = xb  + (size_t)MROWS * HIDDEN;
  unsigned short* wkb = wqb + (size_t)HIDDEN * HIDDEN;
  unsigned short* wvb = wkb + (size_t)HIDDEN * HIDDEN;
  unsigned short* wob = wvb + (size_t)HIDDEN * HIDDEN;
  unsigned short* Qb  = wob + (size_t)HIDDEN * HIDDEN;
  unsigned short* Kb  = Qb  + (size_t)MROWS * HIDDEN;
  unsigned short* Vtb = Kb  + (size_t)MROWS * HIDDEN;
  unsigned short* Ob  = Vtb + (size_t)MROWS * HIDDEN;
  (void)wkb;

  constexpr int CVT_THREADS = (MROWS * HIDDEN + 4 * HIDDEN * HIDDEN) / 4;
  k_cvt_all<<<CVT_THREADS / 256, 256, 0, stream>>>(x, Wq, Wk, Wv, Wo, xb);

  // fused Q+K projection + RoPE: 256x256 pipelined, 256 blocks
  k_gemm256<0, 256, 256><<<256, 512, 0, stream>>>(xb, wqb, Qb);
  // V^T projection: 128x256 pipelined (A=Wv, B=x), 256 blocks
  k_gemm256<3, 128, 256><<<256, 512, 0, stream>>>(wvb, xb, Vtb);

  k_attn<<<dim3(SEQ / QB, BATCH * HEADS), 512, 0, stream>>>(Qb, Kb, Vtb, Ob);

  // output projection: 256x128 pipelined, 256 blocks
  k_gemm256<2, 256, 128><<<256, 512, 0, stream>>>(Ob, wob, out);
}